// Round 4
// baseline (278.616 us; speedup 1.0000x reference)
//
#include <hip/hip_runtime.h>

#define N_NODES 20000
#define N_EDGES 160000
#define CIN     2000
#define N1      500
#define N2      250
#define NH      34     // heads: 1 + 1 + 16 + 16
#define NHP     64

typedef __attribute__((ext_vector_type(4))) float f32x4;
typedef __attribute__((ext_vector_type(8))) __bf16 bf16x8;
typedef __attribute__((ext_vector_type(8))) unsigned short ushort8;

typedef const __attribute__((address_space(1))) void* as1cv;
typedef __attribute__((address_space(3))) void* as3v;

__device__ __forceinline__ unsigned short f2bf(float f) {
    unsigned int u = __builtin_bit_cast(unsigned int, f);
    u += 0x7FFFu + ((u >> 16) & 1u);   // RNE
    return (unsigned short)(u >> 16);
}

__device__ __forceinline__ ushort8 pack8(float4 a, float4 b) {
    ushort8 r;
    r[0] = f2bf(a.x); r[1] = f2bf(a.y); r[2] = f2bf(a.z); r[3] = f2bf(a.w);
    r[4] = f2bf(b.x); r[5] = f2bf(b.y); r[6] = f2bf(b.z); r[7] = f2bf(b.w);
    return r;
}

// ================= K1: prep_w (1280 blocks) || k_init (79 blocks) =================
__global__ __launch_bounds__(256) void k1(const float* __restrict__ W2,
                                          const float* __restrict__ W1,
                                          unsigned int* __restrict__ W2b,
                                          unsigned short* __restrict__ W1T,
                                          float* deg, int* cnt, int* cursor) {
    __shared__ float tile[32][33];
    int b = blockIdx.x, t = threadIdx.x;
    if (b >= 1280) {                    // init
        int i = (b - 1280) * 256 + t;
        if (i < N_NODES) { deg[i] = 1.0f; cnt[i] = 0; cursor[i] = 0; }
        return;
    }
    if (b < 256) {                      // W2 -> bf16 [256][512]
        int idx = b * 256 + t;
        int r = idx >> 8, c = idx & 255;
        int k = c * 2;
        unsigned int o = 0;
        if (r < N2 && k < N1) {
            float2 v = *reinterpret_cast<const float2*>(W2 + (size_t)r * N1 + k);
            o = (unsigned int)f2bf(v.x) | ((unsigned int)f2bf(v.y) << 16);
        }
        W2b[idx] = o;
    } else {                            // transpose W1 [500][2000] -> bf16 [2048][512]
        int bb = b - 256;
        int jt = bb & 15, nt = bb >> 4;
        int c = t & 31, r = t >> 5;
#pragma unroll
        for (int i = 0; i < 4; ++i) {
            int j = jt * 32 + r + i * 8;
            int n = nt * 32 + c;
            tile[r + i * 8][c] = (j < N1 && n < CIN) ? W1[(size_t)j * CIN + n] : 0.f;
        }
        __syncthreads();
#pragma unroll
        for (int i = 0; i < 4; ++i) {
            int n = nt * 32 + r + i * 8;
            int j = jt * 32 + c;
            W1T[(size_t)n * 512 + j] = f2bf(tile[c][r + i * 8]);
        }
    }
}

// ================= K2: gemm W21 (32) || small_vec (1) || k_count (625) =================
__global__ __launch_bounds__(256) void k2(
    const unsigned short* __restrict__ W2b, const unsigned short* __restrict__ W1T,
    float* __restrict__ W21f,
    const int* __restrict__ ei, const float* __restrict__ ew, float* deg, int* cnt,
    const float* __restrict__ W2, const float* __restrict__ b1, const float* __restrict__ b2,
    const float* __restrict__ Wmt, const float* __restrict__ bmt,
    const float* __restrict__ Wst, const float* __restrict__ bst,
    const float* __restrict__ Wmz, const float* __restrict__ bmz,
    const float* __restrict__ Wsz, const float* __restrict__ bsz,
    float* __restrict__ ccdd) {
    __shared__ alignas(16) unsigned short lA[128 * 32];
    __shared__ alignas(16) unsigned short lB[128 * 32];
    const int B = blockIdx.x, t = threadIdx.x;

    if (B >= 33) {                      // ---- k_count ----
        int e = (B - 33) * 256 + t;
        if (e < N_EDGES) {
            int d = ei[N_EDGES + e];
            atomicAdd(&deg[d], ew[e]);
            atomicAdd(&cnt[d], 1);
        }
        return;
    }
    if (B == 32) {                      // ---- small_vec (wave-parallel) ----
        float* c1 = (float*)lA;         // 256 floats
        int w = t >> 6, lane = t & 63;
        for (int r0 = 0; r0 < 252; r0 += 4) {
            int r = r0 + w;
            float a = 0.f;
            if (r < N2) {
                for (int j = lane; j < N1; j += 64) a += W2[(size_t)r * N1 + j] * b1[j];
            }
#pragma unroll
            for (int off = 32; off; off >>= 1) a += __shfl_down(a, off);
            if (lane == 0 && r < N2) c1[r] = a;
        }
        __syncthreads();
        for (int o0 = 0; o0 < 36; o0 += 4) {
            int o = o0 + w;
            float cc = 0.f, dv = 0.f, bias = 0.f;
            if (o < NH) {
                const float* src; int row;
                if (o == 0)      { src = Wmt; row = 0;      bias = bmt[0]; }
                else if (o == 1) { src = Wst; row = 0;      bias = bst[0]; }
                else if (o < 18) { src = Wmz; row = o - 2;  bias = bmz[o - 2]; }
                else             { src = Wsz; row = o - 18; bias = bsz[o - 18]; }
                for (int j = lane; j < N2; j += 64) {
                    float wv = src[(size_t)row * N2 + j];
                    cc += wv * c1[j];
                    dv += wv * b2[j];
                }
            }
#pragma unroll
            for (int off = 32; off; off >>= 1) { cc += __shfl_down(cc, off); dv += __shfl_down(dv, off); }
            if (lane == 0 && o < NH) { ccdd[o] = cc; ccdd[NHP + o] = dv + bias; }
        }
        if (t >= NH && t < NHP) { ccdd[t] = 0.f; ccdd[NHP + t] = 0.f; }
        return;
    }
    // ---- gemm W21 = W2b[256x512] @ W1T[2048x512]^T -> W21f[256][2048] ----
    {
        const int w = t >> 6, lane = t & 63;
        const int bn0 = (B & 15) * 128, bm0 = (B >> 4) * 128;
        const int wr = w >> 1, wc = w & 1;
        const int lr = lane & 15, lk = (lane >> 4) * 8;
        f32x4 acc[4][4];
#pragma unroll
        for (int i = 0; i < 4; i++)
#pragma unroll
            for (int j = 0; j < 4; j++) acc[i][j] = (f32x4){0.f, 0.f, 0.f, 0.f};
        for (int kt = 0; kt < 16; ++kt) {
            const int kb = kt * 32;
#pragma unroll
            for (int i = 0; i < 2; i++) {
                int c0 = i * 256 + w * 64;
                int c  = c0 + lane;
                int rr = c >> 2, kg = c & 3;
                const unsigned short* gp = W2b + (size_t)(bm0 + rr) * 512 + kb + kg * 8;
                __builtin_amdgcn_global_load_lds((as1cv)gp, (as3v)(lA + (size_t)c0 * 8), 16, 0, 0);
            }
#pragma unroll
            for (int i = 0; i < 2; i++) {
                int c0 = i * 256 + w * 64;
                int c  = c0 + lane;
                int rr = c >> 2, kg = c & 3;
                const unsigned short* gp = W1T + (size_t)(bn0 + rr) * 512 + kb + kg * 8;
                __builtin_amdgcn_global_load_lds((as1cv)gp, (as3v)(lB + (size_t)c0 * 8), 16, 0, 0);
            }
            __syncthreads();
            ushort8 af[4], bfr[4];
#pragma unroll
            for (int m = 0; m < 4; m++)
                af[m] = *reinterpret_cast<const ushort8*>(&lA[(wr * 64 + m * 16 + lr) * 32 + lk]);
#pragma unroll
            for (int n = 0; n < 4; n++)
                bfr[n] = *reinterpret_cast<const ushort8*>(&lB[(wc * 64 + n * 16 + lr) * 32 + lk]);
#pragma unroll
            for (int m = 0; m < 4; m++)
#pragma unroll
                for (int n = 0; n < 4; n++)
                    acc[m][n] = __builtin_amdgcn_mfma_f32_16x16x32_bf16(
                        __builtin_bit_cast(bf16x8, af[m]), __builtin_bit_cast(bf16x8, bfr[n]),
                        acc[m][n], 0, 0, 0);
            __syncthreads();
        }
        const int crow0 = bm0 + wr * 64 + (lane >> 4) * 4;
        const int ccol0 = bn0 + wc * 64 + lr;
#pragma unroll
        for (int m = 0; m < 4; m++)
#pragma unroll
            for (int n = 0; n < 4; n++)
#pragma unroll
                for (int rg = 0; rg < 4; rg++)
                    W21f[(size_t)(crow0 + m * 16 + rg) * 2048 + ccol0 + n * 16] = acc[m][n][rg];
    }
}

// ================= K3 (1024 thr): scan_dinv (1) || wt_build (68) =================
__global__ __launch_bounds__(1024) void k3(
    const int* __restrict__ cnt, const float* __restrict__ deg,
    float* __restrict__ dinv, int* __restrict__ rowPtr,
    const float* __restrict__ W21f,
    const float* __restrict__ Wmt, const float* __restrict__ Wst,
    const float* __restrict__ Wmz, const float* __restrict__ Wsz,
    unsigned short* __restrict__ Wtb) {
    __shared__ int partial[1024];
    int t = threadIdx.x;
    if (blockIdx.x == 0) {              // ---- single-pass scan + dinv ----
        int base = t * 20;
        int loc[20]; int s = 0;
#pragma unroll
        for (int i = 0; i < 20; ++i) {
            int idx = base + i;
            int v = 0;
            if (idx < N_NODES) { v = cnt[idx]; dinv[idx] = rsqrtf(deg[idx]); }
            loc[i] = s; s += v;
        }
        partial[t] = s;
        __syncthreads();
        for (int off = 1; off < 1024; off <<= 1) {
            int x = (t >= off) ? partial[t - off] : 0;
            __syncthreads();
            partial[t] += x;
            __syncthreads();
        }
        int pre = (t == 0) ? 0 : partial[t - 1];
#pragma unroll
        for (int i = 0; i < 20; ++i) {
            int idx = base + i;
            if (idx < N_NODES) rowPtr[idx] = pre + loc[i];
        }
        if (t == 1023) rowPtr[N_NODES] = partial[1023];
        return;
    }
    // ---- wt_build: Wt[o][n] = sum_j Wh[o][j] * W21f[j][n] ----
    int b = blockIdx.x - 1;             // 0..67; 2 blocks per o
    int o = b >> 1;
    int n = (b & 1) * 1024 + t;
    float* wh = (float*)partial;
    const float* src = Wmt; int row = 0;
    if (o == 1)                 { src = Wst; row = 0; }
    else if (o >= 2 && o < 18)  { src = Wmz; row = o - 2; }
    else if (o >= 18)           { src = Wsz; row = o - 18; }
    if (t < 256) wh[t] = (t < N2) ? src[(size_t)row * N2 + t] : 0.f;
    __syncthreads();
    float acc = 0.f;
    for (int j = 0; j < N2; ++j) acc += wh[j] * W21f[(size_t)j * 2048 + n];
    Wtb[(size_t)o * 2048 + n] = f2bf(acc);
}

// ================= K4: gemm_T (626 blocks) || k_fill (625 blocks) =================
__global__ __launch_bounds__(256) void k4(
    const float* __restrict__ X, const unsigned short* __restrict__ Wtb,
    float* __restrict__ Tpart,
    const int* __restrict__ ei, const float* __restrict__ ew,
    const float* __restrict__ dinv, const int* __restrict__ rowPtr,
    int* cursor, int* __restrict__ colA, float* __restrict__ valA) {
    __shared__ alignas(16) unsigned short lA[64 * 64];
    __shared__ alignas(16) unsigned short lB[64 * 64];
    const int B = blockIdx.x, t = threadIdx.x;
    if (B >= 626) {                     // ---- k_fill ----
        int e = (B - 626) * 256 + t;
        if (e < N_EDGES) {
            int s = ei[e], d = ei[N_EDGES + e];
            int p = atomicAdd(&cursor[d], 1);
            int j = rowPtr[d] + p;
            colA[j] = s;
            valA[j] = dinv[s] * ew[e] * dinv[d];
        }
        return;
    }
    // ---- gemm_T: Tpart[kp] = X @ Wt^T (64-row tile, N=64, split-K x2) ----
    const int w = t >> 6, lane = t & 63;
    const int kp = B & 1;
    const int bm0 = (B >> 1) * 64;
    const int kbase = kp * 1024;
    const int lr = lane & 15, lkb = (lane >> 4) * 16;

    const int c0 = t, c1 = t + 256;
    const int ar0 = c0 >> 3, ac0 = (c0 & 7) * 8;
    const int ar1 = c1 >> 3, ac1 = (c1 & 7) * 8;
    int gr0 = bm0 + ar0; if (gr0 >= N_NODES) gr0 = N_NODES - 1;
    int gr1 = bm0 + ar1; if (gr1 >= N_NODES) gr1 = N_NODES - 1;
    const float* pA0 = X + (size_t)gr0 * CIN + kbase + ac0;
    const float* pA1 = X + (size_t)gr1 * CIN + kbase + ac1;
    const unsigned short* pB0 = Wtb + ar0 * 2048 + kbase + ac0;
    const unsigned short* pB1 = Wtb + ar1 * 2048 + kbase + ac1;
    char* const LA = (char*)lA;
    char* const LB = (char*)lB;
    char* const wA0 = LA + ((ar0 * 128 + ac0 * 2) ^ ((ar0 & 7) << 4));
    char* const wA1 = LA + ((ar1 * 128 + ac1 * 2) ^ ((ar1 & 7) << 4));
    char* const wB0 = LB + ((ar0 * 128 + ac0 * 2) ^ ((ar0 & 7) << 4));
    char* const wB1 = LB + ((ar1 * 128 + ac1 * 2) ^ ((ar1 & 7) << 4));

    int aoff[4][2], boff[2];
#pragma unroll
    for (int m = 0; m < 4; ++m)
#pragma unroll
        for (int k = 0; k < 2; ++k)
            aoff[m][k] = (((m * 16 + lr) * 128 + k * 64 + lkb) ^ ((lr & 7) << 4));
#pragma unroll
    for (int k = 0; k < 2; ++k)
        boff[k] = (((w * 16 + lr) * 128 + k * 64 + lkb) ^ ((lr & 7) << 4));

    f32x4 acc[4];
#pragma unroll
    for (int m = 0; m < 4; ++m) acc[m] = (f32x4){0.f, 0.f, 0.f, 0.f};

    float4 a00, a01, a10, a11;
    ushort8 bv0, bv1;
    const float4 z4 = make_float4(0.f, 0.f, 0.f, 0.f);

#define STAGE_LOAD(S)                                                              \
    {                                                                              \
        bool v0 = (kbase + ac0 + (S) * 64) < CIN;                                  \
        bool v1 = (kbase + ac1 + (S) * 64) < CIN;                                  \
        const float4* q0 = (const float4*)(v0 ? pA0 + (S) * 64 : (const float*)X); \
        const float4* q1 = (const float4*)(v1 ? pA1 + (S) * 64 : (const float*)X); \
        a00 = q0[0]; a01 = q0[1];                                                  \
        a10 = q1[0]; a11 = q1[1];                                                  \
        if (!v0) { a00 = z4; a01 = z4; }                                           \
        if (!v1) { a10 = z4; a11 = z4; }                                           \
        bv0 = *(const ushort8*)(pB0 + (S) * 64);                                   \
        bv1 = *(const ushort8*)(pB1 + (S) * 64);                                   \
    }

    STAGE_LOAD(0)
    for (int s = 0; s < 16; ++s) {
        __syncthreads();
        *(ushort8*)wA0 = pack8(a00, a01);
        *(ushort8*)wA1 = pack8(a10, a11);
        *(ushort8*)wB0 = bv0;
        *(ushort8*)wB1 = bv1;
        __syncthreads();
        if (s < 15) STAGE_LOAD(s + 1)
#pragma unroll
        for (int k = 0; k < 2; ++k) {
            ushort8 bf = *(const ushort8*)(LB + boff[k]);
#pragma unroll
            for (int m = 0; m < 4; ++m) {
                ushort8 af = *(const ushort8*)(LA + aoff[m][k]);
                acc[m] = __builtin_amdgcn_mfma_f32_16x16x32_bf16(
                    __builtin_bit_cast(bf16x8, af), __builtin_bit_cast(bf16x8, bf),
                    acc[m], 0, 0, 0);
            }
        }
    }
#undef STAGE_LOAD
    float* Tp = Tpart + (size_t)kp * N_NODES * NHP;
    const int col = w * 16 + lr;
    const int rb = bm0 + (lane >> 4) * 4;
#pragma unroll
    for (int m = 0; m < 4; ++m)
#pragma unroll
        for (int rg = 0; rg < 4; ++rg) {
            int row = rb + m * 16 + rg;
            if (row < N_NODES) Tp[(size_t)row * NHP + col] = acc[m][rg];
        }
}

// ================= K5: agg_a with fused split-K reduce =================
__global__ __launch_bounds__(256) void agg_a(
    const float* __restrict__ Tp, const int* __restrict__ rowPtr,
    const int* __restrict__ colA, const float* __restrict__ valA,
    const float* __restrict__ dinv, float* __restrict__ U) {
    const float* __restrict__ T1 = Tp + (size_t)N_NODES * NHP;
    int wid = blockIdx.x * 4 + (threadIdx.x >> 6);
    int lane = threadIdx.x & 63;
    if (wid >= N_NODES) return;
    int d = wid;
    float dv = dinv[d];
    float acc = dv * dv * (Tp[(size_t)d * NHP + lane] + T1[(size_t)d * NHP + lane]);
    int e0 = rowPtr[d], e1 = rowPtr[d + 1];
    int e = e0;
    for (; e + 4 <= e1; e += 4) {
        int s0 = colA[e], s1 = colA[e + 1], s2 = colA[e + 2], s3 = colA[e + 3];
        float w0 = valA[e], w1 = valA[e + 1], w2 = valA[e + 2], w3 = valA[e + 3];
        float t0 = Tp[(size_t)s0 * NHP + lane] + T1[(size_t)s0 * NHP + lane];
        float t1 = Tp[(size_t)s1 * NHP + lane] + T1[(size_t)s1 * NHP + lane];
        float t2 = Tp[(size_t)s2 * NHP + lane] + T1[(size_t)s2 * NHP + lane];
        float t3 = Tp[(size_t)s3 * NHP + lane] + T1[(size_t)s3 * NHP + lane];
        acc += w0 * t0 + w1 * t1 + w2 * t2 + w3 * t3;
    }
    for (; e < e1; ++e) {
        int s = colA[e];
        acc += valA[e] * (Tp[(size_t)s * NHP + lane] + T1[(size_t)s * NHP + lane]);
    }
    U[(size_t)d * NHP + lane] = acc;
}

// ================= K6: agg_b: out = act( A_hat @ U + rowsum*cc + dd ) =================
__global__ __launch_bounds__(256) void agg_b(
    const float* __restrict__ U, const int* __restrict__ rowPtr,
    const int* __restrict__ colA, const float* __restrict__ valA,
    const float* __restrict__ dinv, const float* __restrict__ ccdd,
    float* __restrict__ out) {
    int wid = blockIdx.x * 4 + (threadIdx.x >> 6);
    int lane = threadIdx.x & 63;
    if (wid >= N_NODES) return;
    int d = wid;
    float dv = dinv[d], self = dv * dv;
    float acc = self * U[(size_t)d * NHP + lane];
    float r = self;
    int e0 = rowPtr[d], e1 = rowPtr[d + 1];
    int e = e0;
    for (; e + 4 <= e1; e += 4) {
        int s0 = colA[e], s1 = colA[e + 1], s2 = colA[e + 2], s3 = colA[e + 3];
        float w0 = valA[e], w1 = valA[e + 1], w2 = valA[e + 2], w3 = valA[e + 3];
        float t0 = U[(size_t)s0 * NHP + lane];
        float t1 = U[(size_t)s1 * NHP + lane];
        float t2 = U[(size_t)s2 * NHP + lane];
        float t3 = U[(size_t)s3 * NHP + lane];
        acc += w0 * t0 + w1 * t1 + w2 * t2 + w3 * t3;
        r += w0 + w1 + w2 + w3;
    }
    for (; e < e1; ++e) {
        int s = colA[e];
        float wv = valA[e];
        acc += wv * U[(size_t)s * NHP + lane];
        r += wv;
    }
    if (lane < NH) {
        float v = acc + r * ccdd[lane] + ccdd[NHP + lane];
        if (lane < 2 || lane >= 18)
            v = fmaxf(v, 0.f) + log1pf(expf(-fabsf(v)));
        size_t oidx;
        if (lane == 0)      oidx = (size_t)d;
        else if (lane == 1) oidx = (size_t)N_NODES + d;
        else if (lane < 18) oidx = (size_t)2 * N_NODES + (size_t)d * 16 + (lane - 2);
        else                oidx = (size_t)18 * N_NODES + (size_t)d * 16 + (lane - 18);
        out[oidx] = v;
    }
}

extern "C" void kernel_launch(void* const* d_in, const int* in_sizes, int n_in,
                              void* d_out, int out_size, void* d_ws, size_t ws_size,
                              hipStream_t stream) {
    const float* X   = (const float*)d_in[0];
    const int*   EI  = (const int*)d_in[1];
    const float* EW  = (const float*)d_in[2];
    const float* W1  = (const float*)d_in[3];
    const float* b1  = (const float*)d_in[4];
    const float* W2  = (const float*)d_in[5];
    const float* b2  = (const float*)d_in[6];
    const float* Wmt = (const float*)d_in[7];
    const float* bmt = (const float*)d_in[8];
    const float* Wst = (const float*)d_in[9];
    const float* bst = (const float*)d_in[10];
    const float* Wmz = (const float*)d_in[11];
    const float* bmz = (const float*)d_in[12];
    const float* Wsz = (const float*)d_in[13];
    const float* bsz = (const float*)d_in[14];
    float* out = (float*)d_out;

    char* ws = (char*)d_ws;
    size_t off = 0;
    auto alloc = [&](size_t bytes) -> char* {
        char* p = ws + off;
        off += (bytes + 255) & ~(size_t)255;
        return p;
    };
    unsigned short* W2b  = (unsigned short*)alloc((size_t)256 * 512 * 2);
    unsigned short* W1T  = (unsigned short*)alloc((size_t)2048 * 512 * 2);
    float*          W21f = (float*)alloc((size_t)256 * 2048 * 4);
    unsigned short* Wtb  = (unsigned short*)alloc((size_t)NHP * 2048 * 2);
    float*          ccdd = (float*)alloc(2 * NHP * 4);
    float*          Tp   = (float*)alloc((size_t)2 * N_NODES * NHP * 4);
    float*          U    = (float*)alloc((size_t)N_NODES * NHP * 4);
    float* deg    = (float*)alloc(N_NODES * 4);
    float* dinv   = (float*)alloc(N_NODES * 4);
    int*   cnt    = (int*)alloc(N_NODES * 4);
    int*   cursor = (int*)alloc(N_NODES * 4);
    int*   rowPtr = (int*)alloc((N_NODES + 1) * 4);
    int*   colA   = (int*)alloc(N_EDGES * 4);
    float* valA   = (float*)alloc(N_EDGES * 4);
    if (off > ws_size) return;   // loud failure: d_out stays poisoned

    k1<<<1280 + 79, 256, 0, stream>>>(W2, W1, (unsigned int*)W2b, W1T, deg, cnt, cursor);
    k2<<<33 + 625, 256, 0, stream>>>(W2b, W1T, W21f, EI, EW, deg, cnt,
                                     W2, b1, b2, Wmt, bmt, Wst, bst, Wmz, bmz, Wsz, bsz, ccdd);
    k3<<<1 + 68, 1024, 0, stream>>>(cnt, deg, dinv, rowPtr, W21f, Wmt, Wst, Wmz, Wsz, Wtb);
    k4<<<626 + 625, 256, 0, stream>>>(X, Wtb, Tp, EI, EW, dinv, rowPtr, cursor, colA, valA);
    agg_a<<<(N_NODES + 3) / 4, 256, 0, stream>>>(Tp, rowPtr, colA, valA, dinv, U);
    agg_b<<<(N_NODES + 3) / 4, 256, 0, stream>>>(U, rowPtr, colA, valA, dinv, ccdd, out);
}

// Round 5
// 150.569 us; speedup vs baseline: 1.8504x; 1.8504x over previous
//
#include <hip/hip_runtime.h>

#define N_NODES 20000
#define N_EDGES 160000
#define CIN     2000
#define N1      500
#define N2      250
#define NH      34     // heads: 1 + 1 + 16 + 16
#define NHP     64

typedef __attribute__((ext_vector_type(4))) float f32x4;
typedef __attribute__((ext_vector_type(8))) __bf16 bf16x8;
typedef __attribute__((ext_vector_type(8))) unsigned short ushort8;

typedef const __attribute__((address_space(1))) void* as1cv;
typedef __attribute__((address_space(3))) void* as3v;

__device__ __forceinline__ unsigned short f2bf(float f) {
    unsigned int u = __builtin_bit_cast(unsigned int, f);
    u += 0x7FFFu + ((u >> 16) & 1u);   // RNE
    return (unsigned short)(u >> 16);
}

__device__ __forceinline__ ushort8 pack8(float4 a, float4 b) {
    ushort8 r;
    r[0] = f2bf(a.x); r[1] = f2bf(a.y); r[2] = f2bf(a.z); r[3] = f2bf(a.w);
    r[4] = f2bf(b.x); r[5] = f2bf(b.y); r[6] = f2bf(b.z); r[7] = f2bf(b.w);
    return r;
}

// ================= K1: prep_w (1280 blocks) || k_init (79 blocks) =================
__global__ __launch_bounds__(256) void k1(const float* __restrict__ W2,
                                          const float* __restrict__ W1,
                                          unsigned int* __restrict__ W2b,
                                          unsigned short* __restrict__ W1T,
                                          float* deg, int* cnt, int* cursor) {
    __shared__ float tile[32][33];
    int b = blockIdx.x, t = threadIdx.x;
    if (b >= 1280) {                    // init
        int i = (b - 1280) * 256 + t;
        if (i < N_NODES) { deg[i] = 1.0f; cnt[i] = 0; cursor[i] = 0; }
        return;
    }
    if (b < 256) {                      // W2 -> bf16 [256][512]
        int idx = b * 256 + t;
        int r = idx >> 8, c = idx & 255;
        int k = c * 2;
        unsigned int o = 0;
        if (r < N2 && k < N1) {
            float2 v = *reinterpret_cast<const float2*>(W2 + (size_t)r * N1 + k);
            o = (unsigned int)f2bf(v.x) | ((unsigned int)f2bf(v.y) << 16);
        }
        W2b[idx] = o;
    } else {                            // transpose W1 [500][2000] -> bf16 [2048][512]
        int bb = b - 256;
        int jt = bb & 15, nt = bb >> 4;
        int c = t & 31, r = t >> 5;
#pragma unroll
        for (int i = 0; i < 4; ++i) {
            int j = jt * 32 + r + i * 8;
            int n = nt * 32 + c;
            tile[r + i * 8][c] = (j < N1 && n < CIN) ? W1[(size_t)j * CIN + n] : 0.f;
        }
        __syncthreads();
#pragma unroll
        for (int i = 0; i < 4; ++i) {
            int n = nt * 32 + r + i * 8;
            int j = jt * 32 + c;
            W1T[(size_t)n * 512 + j] = f2bf(tile[c][r + i * 8]);
        }
    }
}

// ================= K2: gemm W21 (32 blocks) || k_count (625 blocks) =================
__global__ __launch_bounds__(256) void k2(
    const unsigned short* __restrict__ W2b, const unsigned short* __restrict__ W1T,
    float* __restrict__ W21f,
    const int* __restrict__ ei, const float* __restrict__ ew, float* deg, int* cnt) {
    __shared__ alignas(16) unsigned short lA[128 * 32];
    __shared__ alignas(16) unsigned short lB[128 * 32];
    const int B = blockIdx.x, t = threadIdx.x;

    if (B >= 32) {                      // ---- k_count ----
        int e = (B - 32) * 256 + t;
        if (e < N_EDGES) {
            int d = ei[N_EDGES + e];
            atomicAdd(&deg[d], ew[e]);
            atomicAdd(&cnt[d], 1);
        }
        return;
    }
    // ---- gemm W21 = W2b[256x512] @ W1T[2048x512]^T -> W21f[256][2048] ----
    const int w = t >> 6, lane = t & 63;
    const int bn0 = (B & 15) * 128, bm0 = (B >> 4) * 128;
    const int wr = w >> 1, wc = w & 1;
    const int lr = lane & 15, lk = (lane >> 4) * 8;
    f32x4 acc[4][4];
#pragma unroll
    for (int i = 0; i < 4; i++)
#pragma unroll
        for (int j = 0; j < 4; j++) acc[i][j] = (f32x4){0.f, 0.f, 0.f, 0.f};
    for (int kt = 0; kt < 16; ++kt) {
        const int kb = kt * 32;
#pragma unroll
        for (int i = 0; i < 2; i++) {
            int c0 = i * 256 + w * 64;
            int c  = c0 + lane;
            int rr = c >> 2, kg = c & 3;
            const unsigned short* gp = W2b + (size_t)(bm0 + rr) * 512 + kb + kg * 8;
            __builtin_amdgcn_global_load_lds((as1cv)gp, (as3v)(lA + (size_t)c0 * 8), 16, 0, 0);
        }
#pragma unroll
        for (int i = 0; i < 2; i++) {
            int c0 = i * 256 + w * 64;
            int c  = c0 + lane;
            int rr = c >> 2, kg = c & 3;
            const unsigned short* gp = W1T + (size_t)(bn0 + rr) * 512 + kb + kg * 8;
            __builtin_amdgcn_global_load_lds((as1cv)gp, (as3v)(lB + (size_t)c0 * 8), 16, 0, 0);
        }
        __syncthreads();
        ushort8 af[4], bfr[4];
#pragma unroll
        for (int m = 0; m < 4; m++)
            af[m] = *reinterpret_cast<const ushort8*>(&lA[(wr * 64 + m * 16 + lr) * 32 + lk]);
#pragma unroll
        for (int n = 0; n < 4; n++)
            bfr[n] = *reinterpret_cast<const ushort8*>(&lB[(wc * 64 + n * 16 + lr) * 32 + lk]);
#pragma unroll
        for (int m = 0; m < 4; m++)
#pragma unroll
            for (int n = 0; n < 4; n++)
                acc[m][n] = __builtin_amdgcn_mfma_f32_16x16x32_bf16(
                    __builtin_bit_cast(bf16x8, af[m]), __builtin_bit_cast(bf16x8, bfr[n]),
                    acc[m][n], 0, 0, 0);
        __syncthreads();
    }
    const int crow0 = bm0 + wr * 64 + (lane >> 4) * 4;
    const int ccol0 = bn0 + wc * 64 + lr;
#pragma unroll
    for (int m = 0; m < 4; m++)
#pragma unroll
        for (int n = 0; n < 4; n++)
#pragma unroll
            for (int rg = 0; rg < 4; rg++)
                W21f[(size_t)(crow0 + m * 16 + rg) * 2048 + ccol0 + n * 16] = acc[m][n][rg];
}

// ================= K3 (1024 thr): scan_dinv (1) || wt_build (68) =================
__global__ __launch_bounds__(1024) void k3(
    const int* __restrict__ cnt, const float* __restrict__ deg,
    float* __restrict__ dinv, int* __restrict__ rowPtr,
    const float* __restrict__ W21f,
    const float* __restrict__ Wmt, const float* __restrict__ Wst,
    const float* __restrict__ Wmz, const float* __restrict__ Wsz,
    unsigned short* __restrict__ Wtb) {
    __shared__ int partial[1024];
    int t = threadIdx.x;
    if (blockIdx.x == 0) {              // ---- single-pass scan + dinv ----
        int base = t * 20;
        int loc[20]; int s = 0;
#pragma unroll
        for (int i = 0; i < 20; ++i) {
            int idx = base + i;
            int v = 0;
            if (idx < N_NODES) { v = cnt[idx]; dinv[idx] = rsqrtf(deg[idx]); }
            loc[i] = s; s += v;
        }
        partial[t] = s;
        __syncthreads();
        for (int off = 1; off < 1024; off <<= 1) {
            int x = (t >= off) ? partial[t - off] : 0;
            __syncthreads();
            partial[t] += x;
            __syncthreads();
        }
        int pre = (t == 0) ? 0 : partial[t - 1];
#pragma unroll
        for (int i = 0; i < 20; ++i) {
            int idx = base + i;
            if (idx < N_NODES) rowPtr[idx] = pre + loc[i];
        }
        if (t == 1023) rowPtr[N_NODES] = partial[1023];
        return;
    }
    // ---- wt_build: Wt[o][n] = sum_j Wh[o][j] * W21f[j][n] ----
    int b = blockIdx.x - 1;             // 0..67; 2 blocks per o
    int o = b >> 1;
    int n = (b & 1) * 1024 + t;
    float* wh = (float*)partial;
    const float* src = Wmt; int row = 0;
    if (o == 1)                 { src = Wst; row = 0; }
    else if (o >= 2 && o < 18)  { src = Wmz; row = o - 2; }
    else if (o >= 18)           { src = Wsz; row = o - 18; }
    if (t < 256) wh[t] = (t < N2) ? src[(size_t)row * N2 + t] : 0.f;
    __syncthreads();
    float acc = 0.f;
    for (int j = 0; j < N2; ++j) acc += wh[j] * W21f[(size_t)j * 2048 + n];
    Wtb[(size_t)o * 2048 + n] = f2bf(acc);
}

// ====== K4: gemm_T (626) || k_fill (625) || small_vec (1 block, hidden straggler) ======
__global__ __launch_bounds__(256) void k4(
    const float* __restrict__ X, const unsigned short* __restrict__ Wtb,
    float* __restrict__ Tpart,
    const int* __restrict__ ei, const float* __restrict__ ew,
    const float* __restrict__ dinv, const int* __restrict__ rowPtr,
    int* cursor, int* __restrict__ colA, float* __restrict__ valA,
    const float* __restrict__ W2, const float* __restrict__ b1, const float* __restrict__ b2,
    const float* __restrict__ Wmt, const float* __restrict__ bmt,
    const float* __restrict__ Wst, const float* __restrict__ bst,
    const float* __restrict__ Wmz, const float* __restrict__ bmz,
    const float* __restrict__ Wsz, const float* __restrict__ bsz,
    float* __restrict__ ccdd) {
    __shared__ alignas(16) unsigned short lA[64 * 64];
    __shared__ alignas(16) unsigned short lB[64 * 64];
    const int B = blockIdx.x, t = threadIdx.x;
    if (B == 1251) {                    // ---- small_vec: cc = Wh W2 b1, dd = Wh b2 + bh ----
        float* c1s = (float*)lA;        // 256 floats
        float* b2s = ((float*)lA) + 256;
        float* b1s = (float*)lB;        // 512 floats
        if (t < N2) b2s[t] = b2[t];
        b1s[t] = (t < N1) ? b1[t] : 0.f;
        b1s[t + 256] = (t + 256 < N1) ? b1[t + 256] : 0.f;
        __syncthreads();
        float a = 0.f;
        if (t < N2) {
            const float4* wr4 = (const float4*)(W2 + (size_t)t * N1);   // 2000B rows, 16B aligned
#pragma unroll 5
            for (int j = 0; j < 125; ++j) {
                float4 w4 = wr4[j];
                a += w4.x * b1s[4 * j] + w4.y * b1s[4 * j + 1]
                   + w4.z * b1s[4 * j + 2] + w4.w * b1s[4 * j + 3];
            }
        }
        __syncthreads();
        c1s[t] = (t < N2) ? a : 0.f;
        __syncthreads();
        if (t < NH) {
            const float* src; int row; float bias;
            if (t == 0)      { src = Wmt; row = 0;      bias = bmt[0]; }
            else if (t == 1) { src = Wst; row = 0;      bias = bst[0]; }
            else if (t < 18) { src = Wmz; row = t - 2;  bias = bmz[t - 2]; }
            else             { src = Wsz; row = t - 18; bias = bsz[t - 18]; }
            float cc = 0.f, dv = bias;
            const float2* wr2 = (const float2*)(src + (size_t)row * N2);  // 1000B rows, 8B aligned
#pragma unroll 5
            for (int j = 0; j < 125; ++j) {
                float2 wv = wr2[j];
                cc += wv.x * c1s[2 * j] + wv.y * c1s[2 * j + 1];
                dv += wv.x * b2s[2 * j] + wv.y * b2s[2 * j + 1];
            }
            ccdd[t] = cc;
            ccdd[NHP + t] = dv;
        }
        return;
    }
    if (B >= 626) {                     // ---- k_fill ----
        int e = (B - 626) * 256 + t;
        if (e < N_EDGES) {
            int s = ei[e], d = ei[N_EDGES + e];
            int p = atomicAdd(&cursor[d], 1);
            int j = rowPtr[d] + p;
            colA[j] = s;
            valA[j] = dinv[s] * ew[e] * dinv[d];
        }
        return;
    }
    // ---- gemm_T: Tpart[kp] = X @ Wt^T (64-row tile, N=64, split-K x2) ----
    const int w = t >> 6, lane = t & 63;
    const int kp = B & 1;
    const int bm0 = (B >> 1) * 64;
    const int kbase = kp * 1024;
    const int lr = lane & 15, lkb = (lane >> 4) * 16;

    const int c0 = t, c1 = t + 256;
    const int ar0 = c0 >> 3, ac0 = (c0 & 7) * 8;
    const int ar1 = c1 >> 3, ac1 = (c1 & 7) * 8;
    int gr0 = bm0 + ar0; if (gr0 >= N_NODES) gr0 = N_NODES - 1;
    int gr1 = bm0 + ar1; if (gr1 >= N_NODES) gr1 = N_NODES - 1;
    const float* pA0 = X + (size_t)gr0 * CIN + kbase + ac0;
    const float* pA1 = X + (size_t)gr1 * CIN + kbase + ac1;
    const unsigned short* pB0 = Wtb + ar0 * 2048 + kbase + ac0;
    const unsigned short* pB1 = Wtb + ar1 * 2048 + kbase + ac1;
    char* const LA = (char*)lA;
    char* const LB = (char*)lB;
    char* const wA0 = LA + ((ar0 * 128 + ac0 * 2) ^ ((ar0 & 7) << 4));
    char* const wA1 = LA + ((ar1 * 128 + ac1 * 2) ^ ((ar1 & 7) << 4));
    char* const wB0 = LB + ((ar0 * 128 + ac0 * 2) ^ ((ar0 & 7) << 4));
    char* const wB1 = LB + ((ar1 * 128 + ac1 * 2) ^ ((ar1 & 7) << 4));

    int aoff[4][2], boff[2];
#pragma unroll
    for (int m = 0; m < 4; ++m)
#pragma unroll
        for (int k = 0; k < 2; ++k)
            aoff[m][k] = (((m * 16 + lr) * 128 + k * 64 + lkb) ^ ((lr & 7) << 4));
#pragma unroll
    for (int k = 0; k < 2; ++k)
        boff[k] = (((w * 16 + lr) * 128 + k * 64 + lkb) ^ ((lr & 7) << 4));

    f32x4 acc[4];
#pragma unroll
    for (int m = 0; m < 4; ++m) acc[m] = (f32x4){0.f, 0.f, 0.f, 0.f};

    float4 a00, a01, a10, a11;
    ushort8 bv0, bv1;
    const float4 z4 = make_float4(0.f, 0.f, 0.f, 0.f);

#define STAGE_LOAD(S)                                                              \
    {                                                                              \
        bool v0 = (kbase + ac0 + (S) * 64) < CIN;                                  \
        bool v1 = (kbase + ac1 + (S) * 64) < CIN;                                  \
        const float4* q0 = (const float4*)(v0 ? pA0 + (S) * 64 : (const float*)X); \
        const float4* q1 = (const float4*)(v1 ? pA1 + (S) * 64 : (const float*)X); \
        a00 = q0[0]; a01 = q0[1];                                                  \
        a10 = q1[0]; a11 = q1[1];                                                  \
        if (!v0) { a00 = z4; a01 = z4; }                                           \
        if (!v1) { a10 = z4; a11 = z4; }                                           \
        bv0 = *(const ushort8*)(pB0 + (S) * 64);                                   \
        bv1 = *(const ushort8*)(pB1 + (S) * 64);                                   \
    }

    STAGE_LOAD(0)
    for (int s = 0; s < 16; ++s) {
        __syncthreads();
        *(ushort8*)wA0 = pack8(a00, a01);
        *(ushort8*)wA1 = pack8(a10, a11);
        *(ushort8*)wB0 = bv0;
        *(ushort8*)wB1 = bv1;
        __syncthreads();
        if (s < 15) STAGE_LOAD(s + 1)
#pragma unroll
        for (int k = 0; k < 2; ++k) {
            ushort8 bf = *(const ushort8*)(LB + boff[k]);
#pragma unroll
            for (int m = 0; m < 4; ++m) {
                ushort8 af = *(const ushort8*)(LA + aoff[m][k]);
                acc[m] = __builtin_amdgcn_mfma_f32_16x16x32_bf16(
                    __builtin_bit_cast(bf16x8, af), __builtin_bit_cast(bf16x8, bf),
                    acc[m], 0, 0, 0);
            }
        }
    }
#undef STAGE_LOAD
    float* Tp = Tpart + (size_t)kp * N_NODES * NHP;
    const int col = w * 16 + lr;
    const int rb = bm0 + (lane >> 4) * 4;
#pragma unroll
    for (int m = 0; m < 4; ++m)
#pragma unroll
        for (int rg = 0; rg < 4; ++rg) {
            int row = rb + m * 16 + rg;
            if (row < N_NODES) Tp[(size_t)row * NHP + col] = acc[m][rg];
        }
}

// ================= K5: agg_a with fused split-K reduce =================
__global__ __launch_bounds__(256) void agg_a(
    const float* __restrict__ Tp, const int* __restrict__ rowPtr,
    const int* __restrict__ colA, const float* __restrict__ valA,
    const float* __restrict__ dinv, float* __restrict__ U) {
    const float* __restrict__ T1 = Tp + (size_t)N_NODES * NHP;
    int wid = blockIdx.x * 4 + (threadIdx.x >> 6);
    int lane = threadIdx.x & 63;
    if (wid >= N_NODES) return;
    int d = wid;
    float dv = dinv[d];
    float acc = dv * dv * (Tp[(size_t)d * NHP + lane] + T1[(size_t)d * NHP + lane]);
    int e0 = rowPtr[d], e1 = rowPtr[d + 1];
    int e = e0;
    for (; e + 4 <= e1; e += 4) {
        int s0 = colA[e], s1 = colA[e + 1], s2 = colA[e + 2], s3 = colA[e + 3];
        float w0 = valA[e], w1 = valA[e + 1], w2 = valA[e + 2], w3 = valA[e + 3];
        float t0 = Tp[(size_t)s0 * NHP + lane] + T1[(size_t)s0 * NHP + lane];
        float t1 = Tp[(size_t)s1 * NHP + lane] + T1[(size_t)s1 * NHP + lane];
        float t2 = Tp[(size_t)s2 * NHP + lane] + T1[(size_t)s2 * NHP + lane];
        float t3 = Tp[(size_t)s3 * NHP + lane] + T1[(size_t)s3 * NHP + lane];
        acc += w0 * t0 + w1 * t1 + w2 * t2 + w3 * t3;
    }
    for (; e < e1; ++e) {
        int s = colA[e];
        acc += valA[e] * (Tp[(size_t)s * NHP + lane] + T1[(size_t)s * NHP + lane]);
    }
    U[(size_t)d * NHP + lane] = acc;
}

// ================= K6: agg_b: out = act( A_hat @ U + rowsum*cc + dd ) =================
__global__ __launch_bounds__(256) void agg_b(
    const float* __restrict__ U, const int* __restrict__ rowPtr,
    const int* __restrict__ colA, const float* __restrict__ valA,
    const float* __restrict__ dinv, const float* __restrict__ ccdd,
    float* __restrict__ out) {
    int wid = blockIdx.x * 4 + (threadIdx.x >> 6);
    int lane = threadIdx.x & 63;
    if (wid >= N_NODES) return;
    int d = wid;
    float dv = dinv[d], self = dv * dv;
    float acc = self * U[(size_t)d * NHP + lane];
    float r = self;
    int e0 = rowPtr[d], e1 = rowPtr[d + 1];
    int e = e0;
    for (; e + 4 <= e1; e += 4) {
        int s0 = colA[e], s1 = colA[e + 1], s2 = colA[e + 2], s3 = colA[e + 3];
        float w0 = valA[e], w1 = valA[e + 1], w2 = valA[e + 2], w3 = valA[e + 3];
        float t0 = U[(size_t)s0 * NHP + lane];
        float t1 = U[(size_t)s1 * NHP + lane];
        float t2 = U[(size_t)s2 * NHP + lane];
        float t3 = U[(size_t)s3 * NHP + lane];
        acc += w0 * t0 + w1 * t1 + w2 * t2 + w3 * t3;
        r += w0 + w1 + w2 + w3;
    }
    for (; e < e1; ++e) {
        int s = colA[e];
        float wv = valA[e];
        acc += wv * U[(size_t)s * NHP + lane];
        r += wv;
    }
    if (lane < NH) {
        float v = acc + r * ccdd[lane] + ccdd[NHP + lane];
        if (lane < 2 || lane >= 18)
            v = fmaxf(v, 0.f) + log1pf(expf(-fabsf(v)));
        size_t oidx;
        if (lane == 0)      oidx = (size_t)d;
        else if (lane == 1) oidx = (size_t)N_NODES + d;
        else if (lane < 18) oidx = (size_t)2 * N_NODES + (size_t)d * 16 + (lane - 2);
        else                oidx = (size_t)18 * N_NODES + (size_t)d * 16 + (lane - 18);
        out[oidx] = v;
    }
}

extern "C" void kernel_launch(void* const* d_in, const int* in_sizes, int n_in,
                              void* d_out, int out_size, void* d_ws, size_t ws_size,
                              hipStream_t stream) {
    const float* X   = (const float*)d_in[0];
    const int*   EI  = (const int*)d_in[1];
    const float* EW  = (const float*)d_in[2];
    const float* W1  = (const float*)d_in[3];
    const float* b1  = (const float*)d_in[4];
    const float* W2  = (const float*)d_in[5];
    const float* b2  = (const float*)d_in[6];
    const float* Wmt = (const float*)d_in[7];
    const float* bmt = (const float*)d_in[8];
    const float* Wst = (const float*)d_in[9];
    const float* bst = (const float*)d_in[10];
    const float* Wmz = (const float*)d_in[11];
    const float* bmz = (const float*)d_in[12];
    const float* Wsz = (const float*)d_in[13];
    const float* bsz = (const float*)d_in[14];
    float* out = (float*)d_out;

    char* ws = (char*)d_ws;
    size_t off = 0;
    auto alloc = [&](size_t bytes) -> char* {
        char* p = ws + off;
        off += (bytes + 255) & ~(size_t)255;
        return p;
    };
    unsigned short* W2b  = (unsigned short*)alloc((size_t)256 * 512 * 2);
    unsigned short* W1T  = (unsigned short*)alloc((size_t)2048 * 512 * 2);
    float*          W21f = (float*)alloc((size_t)256 * 2048 * 4);
    unsigned short* Wtb  = (unsigned short*)alloc((size_t)NHP * 2048 * 2);
    float*          ccdd = (float*)alloc(2 * NHP * 4);
    float*          Tp   = (float*)alloc((size_t)2 * N_NODES * NHP * 4);
    float*          U    = (float*)alloc((size_t)N_NODES * NHP * 4);
    float* deg    = (float*)alloc(N_NODES * 4);
    float* dinv   = (float*)alloc(N_NODES * 4);
    int*   cnt    = (int*)alloc(N_NODES * 4);
    int*   cursor = (int*)alloc(N_NODES * 4);
    int*   rowPtr = (int*)alloc((N_NODES + 1) * 4);
    int*   colA   = (int*)alloc(N_EDGES * 4);
    float* valA   = (float*)alloc(N_EDGES * 4);
    if (off > ws_size) return;   // loud failure: d_out stays poisoned

    k1<<<1280 + 79, 256, 0, stream>>>(W2, W1, (unsigned int*)W2b, W1T, deg, cnt, cursor);
    k2<<<32 + 625, 256, 0, stream>>>(W2b, W1T, W21f, EI, EW, deg, cnt);
    k3<<<1 + 68, 1024, 0, stream>>>(cnt, deg, dinv, rowPtr, W21f, Wmt, Wst, Wmz, Wsz, Wtb);
    k4<<<626 + 625 + 1, 256, 0, stream>>>(X, Wtb, Tp, EI, EW, dinv, rowPtr, cursor, colA, valA,
                                          W2, b1, b2, Wmt, bmt, Wst, bst, Wmz, bmz, Wsz, bsz, ccdd);
    agg_a<<<(N_NODES + 3) / 4, 256, 0, stream>>>(Tp, rowPtr, colA, valA, dinv, U);
    agg_b<<<(N_NODES + 3) / 4, 256, 0, stream>>>(U, rowPtr, colA, valA, dinv, ccdd, out);
}